// Round 7
// baseline (201.221 us; speedup 1.0000x reference)
//
#include <hip/hip_runtime.h>

#define NB 4
#define NC 6
#define NF 257
#define NT 2000
#define NG (NB * NF)        // 1028 (b,f) groups
#define NPAIR 15
#define NACC 74             // [0..5] s_diag, [6..11] n_diag, [12+4q..] s_re,s_im,n_re,n_im, [72] sum_ms, [73] sum_mn
#define NCHUNK 2
#define TCH (NT / NCHUNK)   // 1000 t per chunk
#define NP4 (TCH / 4)       // 250 float4 positions per chunk
#define BLK 256
#define CS  (NF * NT)       // channel stride (floats)
#define CS4 (CS / 4)        // channel stride (float4)

typedef float nfloat4 __attribute__((ext_vector_type(4)));  // native vec for nontemporal builtins

// DPP row-shift-right add: lane i += lane (i-N) within its 16-lane row
// (0 beyond row edge). Runs on the VALU pipe, NOT the per-CU LDS pipe.
// NOTE: data accumulates toward HIGHER lanes — after shr8+shr4+shr2 the
// evens-sum of a row is in lane 14, odds-sum in lane 15 (round-6 bug: read 0/1).
template<int CTRL>
__device__ __forceinline__ float dpp_add(float v) {
    int s = __builtin_amdgcn_update_dpp(0, __builtin_bit_cast(int, v), CTRL, 0xF, 0xF, true);
    return v + __builtin_bit_cast(float, s);
}

// ---------------- Kernel A: raw weighted PSD partials per (group, chunk) ----
__global__ __launch_bounds__(BLK, 4) void psd_kernel(
    const float* __restrict__ sr, const float* __restrict__ si,
    const float* __restrict__ ms, const float* __restrict__ mn,
    float* __restrict__ wsp)
{
    constexpr int PC[NPAIR] = {0,0,0,0,0,1,1,1,1,2,2,2,3,3,4};
    constexpr int PE[NPAIR] = {1,2,3,4,5,2,3,4,5,3,4,5,4,5,5};

    const int bx = blockIdx.x;
    const int g  = bx >> 1;
    const int b  = g / NF;
    const int f  = g - b * NF;
    const int tb = (bx & 1) * TCH;
    const int sbase = b * NC * CS + f * NT + tb;
    const int mbase = g * NT + tb;

    const float4* s4r = (const float4*)(sr + sbase);
    const float4* s4i = (const float4*)(si + sbase);
    const float4* m4s = (const float4*)(ms + mbase);
    const float4* m4n = (const float4*)(mn + mbase);

    float acc[NACC];
    #pragma unroll
    for (int i = 0; i < NACC; i++) acc[i] = 0.f;

    // Uniform unconditional load burst: inactive lanes load p=0 but zero
    // their mask weights -> every accumulator term carries a mask factor,
    // so their contribution is exactly 0. No branch around the loads.
    const bool act = threadIdx.x < NP4;
    const int  p   = act ? threadIdx.x : 0;
    {
        float wms[4], wmn[4], rr[NC][4], ii[NC][4];
        {
            const float4 t0 = m4s[p];
            wms[0] = t0.x; wms[1] = t0.y; wms[2] = t0.z; wms[3] = t0.w;
            const float4 t1 = m4n[p];
            wmn[0] = t1.x; wmn[1] = t1.y; wmn[2] = t1.z; wmn[3] = t1.w;
        }
        #pragma unroll
        for (int c = 0; c < NC; c++) {
            const float4 tr = s4r[c * CS4 + p];
            rr[c][0] = tr.x; rr[c][1] = tr.y; rr[c][2] = tr.z; rr[c][3] = tr.w;
            const float4 ti = s4i[c * CS4 + p];
            ii[c][0] = ti.x; ii[c][1] = ti.y; ii[c][2] = ti.z; ii[c][3] = ti.w;
        }
        if (!act) {
            #pragma unroll
            for (int k = 0; k < 4; k++) { wms[k] = 0.f; wmn[k] = 0.f; }
        }
        #pragma unroll
        for (int k = 0; k < 4; k++) { acc[72] += wms[k]; acc[73] += wmn[k]; }
        #pragma unroll
        for (int c = 0; c < NC; c++) {
            #pragma unroll
            for (int k = 0; k < 4; k++) {
                const float d = rr[c][k] * rr[c][k] + ii[c][k] * ii[c][k];
                acc[c]     += d * wms[k];
                acc[6 + c] += d * wmn[k];
            }
        }
        #pragma unroll
        for (int q = 0; q < NPAIR; q++) {
            const int c = PC[q], e = PE[q];
            #pragma unroll
            for (int k = 0; k < 4; k++) {
                const float cr = rr[c][k] * rr[e][k] + ii[c][k] * ii[e][k];
                const float ci = ii[c][k] * rr[e][k] - rr[c][k] * ii[e][k];
                acc[12 + 4 * q + 0] += cr * wms[k];
                acc[12 + 4 * q + 1] += ci * wms[k];
                acc[12 + 4 * q + 2] += cr * wmn[k];
                acc[12 + 4 * q + 3] += ci * wmn[k];
            }
        }
    }

    // In-row DPP reduction (VALU pipe): lane 14 of each 16-lane row ends with
    // the row's evens-sum, lane 15 with the odds-sum.
    #pragma unroll
    for (int i = 0; i < NACC; i++) {
        float v = acc[i];
        v = dpp_add<0x118>(v);   // row_shr:8
        v = dpp_add<0x114>(v);   // row_shr:4
        v = dpp_add<0x112>(v);   // row_shr:2
        acc[i] = v;
    }

    __shared__ float red[32][NACC];
    const int lane16 = threadIdx.x & 15;
    const int ridx   = ((threadIdx.x >> 4) << 1) | (lane16 & 1);  // 0..31
    if (lane16 >= 14) {
        #pragma unroll
        for (int i = 0; i < NACC; i++) red[ridx][i] = acc[i];
    }
    __syncthreads();

    if (threadIdx.x < NACC) {
        float s = 0.f;
        #pragma unroll
        for (int r = 0; r < 32; r++) s += red[r][threadIdx.x];
        wsp[bx * NACC + threadIdx.x] = s;
    }
}

// ---------------- Kernel B: one thread per (b,f) — LU + column solves -------
// __launch_bounds__(64,1): allow high VGPR so nothing spills (round-4 profile
// showed the default cap spilled the whole solve -> 49 us; round-5 fix -> fast).
__global__ __launch_bounds__(64, 1) void solve_kernel(
    const float* __restrict__ wsp, float* __restrict__ wsw)
{
    const int gid = blockIdx.x * 64 + threadIdx.x;
    if (gid >= NG) return;

    constexpr int PC[NPAIR] = {0,0,0,0,0,1,1,1,1,2,2,2,3,3,4};
    constexpr int PE[NPAIR] = {1,2,3,4,5,2,3,4,5,3,4,5,4,5,5};
    constexpr int QIDX[NC][NC] = {
        {-1, 0, 1, 2, 3, 4},
        {-1,-1, 5, 6, 7, 8},
        {-1,-1,-1, 9,10,11},
        {-1,-1,-1,-1,12,13},
        {-1,-1,-1,-1,-1,14},
        {-1,-1,-1,-1,-1,-1}};

    const float* p0 = wsp + (2 * gid) * NACC;
    const float* p1 = p0 + NACC;
    float fin[NACC];
    #pragma unroll
    for (int i = 0; i < NACC; i++) fin[i] = p0[i] + p1[i];

    const float invS = 1.f / (fin[72] + 1e-15f);
    const float invN = 1.f / (fin[73] + 1e-15f);

    // A = normalized psd_n + eps*I
    float Ar[NC][NC], Ai[NC][NC];
    #pragma unroll
    for (int c = 0; c < NC; c++) { Ar[c][c] = fin[6 + c] * invN; Ai[c][c] = 0.f; }
    #pragma unroll
    for (int q = 0; q < NPAIR; q++) {
        const int c = PC[q], e = PE[q];
        const float nre = fin[12 + 4 * q + 2] * invN;
        const float nim = fin[12 + 4 * q + 3] * invN;
        Ar[c][e] = nre;  Ai[c][e] = nim;
        Ar[e][c] = nre;  Ai[e][c] = -nim;
    }
    {
        float trn = 0.f;
        #pragma unroll
        for (int c = 0; c < NC; c++) trn += Ar[c][c];
        const float eps = trn * 1e-7f + 1e-8f;
        #pragma unroll
        for (int c = 0; c < NC; c++) Ar[c][c] += eps;
    }

    // In-place unpivoted LU: L (unit diag) below, U on/above.
    #pragma unroll
    for (int k = 0; k < NC; k++) {
        const float dr = Ar[k][k], di = Ai[k][k];
        const float idn = 1.f / (dr * dr + di * di);
        const float pr = dr * idn, pi = -di * idn;
        #pragma unroll
        for (int i = k + 1; i < NC; i++) {
            const float lr = Ar[i][k] * pr - Ai[i][k] * pi;
            const float li = Ar[i][k] * pi + Ai[i][k] * pr;
            Ar[i][k] = lr; Ai[i][k] = li;
            #pragma unroll
            for (int j = k + 1; j < NC; j++) {
                Ar[i][j] -= lr * Ar[k][j] - li * Ai[k][j];
                Ai[i][j] -= lr * Ai[k][j] + li * Ar[k][j];
            }
        }
    }

    // Column-by-column solve of A x = b_j (b_j = col j of normalized psd_s).
    float trr = 1e-8f, tri = 0.f;   // TIK_EPS on real part of trace
    float w0r[NC], w0i[NC];
    #pragma unroll
    for (int j = 0; j < NC; j++) {
        float xr[NC], xi[NC];
        #pragma unroll
        for (int i = 0; i < NC; i++) {
            if (i == j)      { xr[i] = fin[j] * invS;                      xi[i] = 0.f; }
            else if (i < j)  { const int q = QIDX[i][j];
                               xr[i] = fin[12 + 4 * q] * invS;  xi[i] =  fin[13 + 4 * q] * invS; }
            else             { const int q = QIDX[j][i];
                               xr[i] = fin[12 + 4 * q] * invS;  xi[i] = -fin[13 + 4 * q] * invS; }
        }
        #pragma unroll
        for (int i = 1; i < NC; i++) {
            #pragma unroll
            for (int k = 0; k < NC - 1; k++) if (k < i) {
                xr[i] -= Ar[i][k] * xr[k] - Ai[i][k] * xi[k];
                xi[i] -= Ar[i][k] * xi[k] + Ai[i][k] * xr[k];
            }
        }
        #pragma unroll
        for (int i = NC - 1; i >= 0; i--) {
            #pragma unroll
            for (int k = 0; k < NC; k++) if (k > i) {
                xr[i] -= Ar[i][k] * xr[k] - Ai[i][k] * xi[k];
                xi[i] -= Ar[i][k] * xi[k] + Ai[i][k] * xr[k];
            }
            const float dr = Ar[i][i], di = Ai[i][i];
            const float idn = 1.f / (dr * dr + di * di);
            const float pr = dr * idn, pi = -di * idn;
            const float tr0 = xr[i] * pr - xi[i] * pi;
            xi[i] = xr[i] * pi + xi[i] * pr;
            xr[i] = tr0;
        }
        trr += xr[j]; tri += xi[j];
        if (j == 0) {
            #pragma unroll
            for (int i = 0; i < NC; i++) { w0r[i] = xr[i]; w0i[i] = xi[i]; }
        }
    }

    const float idn = 1.f / (trr * trr + tri * tri);
    #pragma unroll
    for (int c = 0; c < NC; c++) {
        const float wre = (w0r[c] * trr + w0i[c] * tri) * idn;
        const float wim = (w0i[c] * trr - w0r[c] * tri) * idn;
        wsw[gid * 12 + c]     = wre;    // conj(w): real
        wsw[gid * 12 + 6 + c] = -wim;   // conj(w): imag
    }
}

// ---------------- Kernel C: enh[t] = sum_c conj(w[c]) * spec[c,t] -----------
__global__ __launch_bounds__(BLK) void apply_kernel(
    const float* __restrict__ sr, const float* __restrict__ si,
    const float* __restrict__ wsw, float* __restrict__ out)
{
    const int bx = blockIdx.x;
    const int g  = bx >> 1;
    const int b  = g / NF;
    const int f  = g - b * NF;
    const int tb = (bx & 1) * TCH;
    const int sbase = b * NC * CS + f * NT + tb;

    const float4* s4r = (const float4*)(sr + sbase);
    const float4* s4i = (const float4*)(si + sbase);

    float wr[NC], wi[NC];
    #pragma unroll
    for (int c = 0; c < NC; c++) {
        wr[c] = wsw[g * 12 + c];
        wi[c] = wsw[g * 12 + 6 + c];
    }

    nfloat4* o4 = (nfloat4*)(out + 2 * (g * NT + tb));

    const int p = threadIdx.x;
    if (p < NP4) {
        float rr[NC][4], ii[NC][4];
        #pragma unroll
        for (int c = 0; c < NC; c++) {
            const float4 tr = s4r[c * CS4 + p];
            rr[c][0] = tr.x; rr[c][1] = tr.y; rr[c][2] = tr.z; rr[c][3] = tr.w;
            const float4 ti = s4i[c * CS4 + p];
            ii[c][0] = ti.x; ii[c][1] = ti.y; ii[c][2] = ti.z; ii[c][3] = ti.w;
        }
        float er[4], ei[4];
        #pragma unroll
        for (int k = 0; k < 4; k++) {
            float a = 0.f, bb = 0.f;
            #pragma unroll
            for (int c = 0; c < NC; c++) {
                a  += wr[c] * rr[c][k] - wi[c] * ii[c][k];
                bb += wr[c] * ii[c][k] + wi[c] * rr[c][k];
            }
            er[k] = a; ei[k] = bb;
        }
        nfloat4 o0 = {er[0], ei[0], er[1], ei[1]};
        nfloat4 o1 = {er[2], ei[2], er[3], ei[3]};
        __builtin_nontemporal_store(o0, &o4[2 * p]);
        __builtin_nontemporal_store(o1, &o4[2 * p + 1]);
    }
}

extern "C" void kernel_launch(void* const* d_in, const int* in_sizes, int n_in,
                              void* d_out, int out_size, void* d_ws, size_t ws_size,
                              hipStream_t stream) {
    const float* sr = (const float*)d_in[0];
    const float* si = (const float*)d_in[1];
    const float* ms = (const float*)d_in[2];
    const float* mn = (const float*)d_in[3];
    float* out = (float*)d_out;

    float* wsp = (float*)d_ws;                       // [NG*NCHUNK][NACC] partials
    float* wsw = wsp + NG * NCHUNK * NACC;           // [NG][12] conj(w)

    psd_kernel<<<NG * NCHUNK, BLK, 0, stream>>>(sr, si, ms, mn, wsp);
    solve_kernel<<<(NG + 63) / 64, 64, 0, stream>>>(wsp, wsw);
    apply_kernel<<<NG * NCHUNK, BLK, 0, stream>>>(sr, si, wsw, out);
}

// Round 8
// 186.636 us; speedup vs baseline: 1.0781x; 1.0781x over previous
//
#include <hip/hip_runtime.h>

#define NB 4
#define NC 6
#define NF 257
#define NT 2000
#define NG (NB * NF)        // 1028 (b,f) groups
#define NPAIR 15
#define NACC 74             // [0..5] s_diag, [6..11] n_diag, [12+4q..] s_re,s_im,n_re,n_im, [72] sum_ms, [73] sum_mn
#define NP4G (NT / 4)       // 500 float4 positions per group
#define NIT 8               // ceil(500/64) pipeline iterations
#define NCHUNK 2
#define TCH (NT / NCHUNK)   // 1000 t per chunk (apply)
#define NP4 (TCH / 4)       // 250 float4 positions per chunk (apply)
#define BLK 256
#define CS  (NF * NT)       // channel stride (floats)
#define CS4 (CS / 4)        // channel stride (float4)

typedef float nfloat4 __attribute__((ext_vector_type(4)));  // native vec for nontemporal builtins

// DPP row-shift-right add: lane i += lane (i-N) within its 16-lane row
// (0 beyond row edge). VALU pipe. Data accumulates toward HIGHER lanes:
// after shr8+shr4+shr2, lane14 = row evens-sum, lane15 = row odds-sum
// (verified on HW in round 7).
template<int CTRL>
__device__ __forceinline__ float dpp_add(float v) {
    int s = __builtin_amdgcn_update_dpp(0, __builtin_bit_cast(int, v), CTRL, 0xF, 0xF, true);
    return v + __builtin_bit_cast(float, s);
}

// ---------------- Kernel A: one WAVE per (b,f) group ------------------------
// 64-thread blocks; 8-iteration t-loop with explicit 2-deep double buffer so
// loads for iter k+1 are in flight while computing iter k. No cross-wave
// reduction, no LDS, no barrier. launch_bounds(64,1): VGPR free (we need only
// ~4 waves/CU; 1028 waves ~= 1 per SIMD device-wide).
__global__ __launch_bounds__(64, 1) void psd_kernel(
    const float* __restrict__ sr, const float* __restrict__ si,
    const float* __restrict__ ms, const float* __restrict__ mn,
    float* __restrict__ wsp)
{
    constexpr int PC[NPAIR] = {0,0,0,0,0,1,1,1,1,2,2,2,3,3,4};
    constexpr int PE[NPAIR] = {1,2,3,4,5,2,3,4,5,3,4,5,4,5,5};

    const int g  = blockIdx.x;
    const int b  = g / NF;
    const int f  = g - b * NF;
    const int sbase = b * NC * CS + f * NT;
    const int mbase = g * NT;

    const float4* s4r = (const float4*)(sr + sbase);
    const float4* s4i = (const float4*)(si + sbase);
    const float4* m4s = (const float4*)(ms + mbase);
    const float4* m4n = (const float4*)(mn + mbase);

    const int lane = threadIdx.x;   // block == 1 wave

    float acc[NACC];
    #pragma unroll
    for (int i = 0; i < NACC; i++) acc[i] = 0.f;

    float4 bm[2][2];          // [buf][ms/mn]
    float4 brr[2][NC], bii[2][NC];

    auto do_load = [&](int it, int u) {
        const int praw = lane + 64 * it;
        const int p = (praw < NP4G) ? praw : 0;   // clamp; masked in compute
        bm[u][0] = m4s[p];
        bm[u][1] = m4n[p];
        #pragma unroll
        for (int c = 0; c < NC; c++) {
            brr[u][c] = s4r[c * CS4 + p];
            bii[u][c] = s4i[c * CS4 + p];
        }
    };

    auto do_compute = [&](int it, int u) {
        const bool act = (lane + 64 * it) < NP4G;
        float wms[4], wmn[4];
        wms[0] = bm[u][0].x; wms[1] = bm[u][0].y; wms[2] = bm[u][0].z; wms[3] = bm[u][0].w;
        wmn[0] = bm[u][1].x; wmn[1] = bm[u][1].y; wmn[2] = bm[u][1].z; wmn[3] = bm[u][1].w;
        if (!act) {
            #pragma unroll
            for (int k = 0; k < 4; k++) { wms[k] = 0.f; wmn[k] = 0.f; }
        }
        float rr[NC][4], ii[NC][4];
        #pragma unroll
        for (int c = 0; c < NC; c++) {
            rr[c][0] = brr[u][c].x; rr[c][1] = brr[u][c].y; rr[c][2] = brr[u][c].z; rr[c][3] = brr[u][c].w;
            ii[c][0] = bii[u][c].x; ii[c][1] = bii[u][c].y; ii[c][2] = bii[u][c].z; ii[c][3] = bii[u][c].w;
        }
        #pragma unroll
        for (int k = 0; k < 4; k++) { acc[72] += wms[k]; acc[73] += wmn[k]; }
        #pragma unroll
        for (int c = 0; c < NC; c++) {
            #pragma unroll
            for (int k = 0; k < 4; k++) {
                const float d = rr[c][k] * rr[c][k] + ii[c][k] * ii[c][k];
                acc[c]     += d * wms[k];
                acc[6 + c] += d * wmn[k];
            }
        }
        #pragma unroll
        for (int q = 0; q < NPAIR; q++) {
            const int c = PC[q], e = PE[q];
            #pragma unroll
            for (int k = 0; k < 4; k++) {
                const float cr = rr[c][k] * rr[e][k] + ii[c][k] * ii[e][k];
                const float ci = ii[c][k] * rr[e][k] - rr[c][k] * ii[e][k];
                acc[12 + 4 * q + 0] += cr * wms[k];
                acc[12 + 4 * q + 1] += ci * wms[k];
                acc[12 + 4 * q + 2] += cr * wmn[k];
                acc[12 + 4 * q + 3] += ci * wmn[k];
            }
        }
    };

    do_load(0, 0);
    #pragma unroll
    for (int it = 0; it < NIT; ++it) {
        if (it + 1 < NIT) do_load(it + 1, (it + 1) & 1);
        do_compute(it, it & 1);
    }

    // Full 64-lane reduce: 3 DPP stages within each 16-row, then xor-16/32
    // combines the 4 rows. After this, lane14 = evens-total, lane15 = odds-total.
    #pragma unroll
    for (int i = 0; i < NACC; i++) {
        float v = acc[i];
        v = dpp_add<0x118>(v);   // row_shr:8
        v = dpp_add<0x114>(v);   // row_shr:4
        v = dpp_add<0x112>(v);   // row_shr:2
        v += __shfl_xor(v, 16);
        v += __shfl_xor(v, 32);
        acc[i] = v;
    }
    if (lane == 14 || lane == 15) {
        #pragma unroll
        for (int i = 0; i < NACC; i++)
            wsp[g * (2 * NACC) + 2 * i + (lane & 1)] = acc[i];
    }
}

// ---------------- Kernel B: one thread per (b,f) — LU + column solves -------
// launch_bounds(64,1): high VGPR allowed so nothing spills (round-4 lesson).
__global__ __launch_bounds__(64, 1) void solve_kernel(
    const float* __restrict__ wsp, float* __restrict__ wsw)
{
    const int gid = blockIdx.x * 64 + threadIdx.x;
    if (gid >= NG) return;

    constexpr int PC[NPAIR] = {0,0,0,0,0,1,1,1,1,2,2,2,3,3,4};
    constexpr int PE[NPAIR] = {1,2,3,4,5,2,3,4,5,3,4,5,4,5,5};
    constexpr int QIDX[NC][NC] = {
        {-1, 0, 1, 2, 3, 4},
        {-1,-1, 5, 6, 7, 8},
        {-1,-1,-1, 9,10,11},
        {-1,-1,-1,-1,12,13},
        {-1,-1,-1,-1,-1,14},
        {-1,-1,-1,-1,-1,-1}};

    const float* pg = wsp + gid * (2 * NACC);
    float fin[NACC];
    #pragma unroll
    for (int i = 0; i < NACC; i++) fin[i] = pg[2 * i] + pg[2 * i + 1];

    const float invS = 1.f / (fin[72] + 1e-15f);
    const float invN = 1.f / (fin[73] + 1e-15f);

    // A = normalized psd_n + eps*I
    float Ar[NC][NC], Ai[NC][NC];
    #pragma unroll
    for (int c = 0; c < NC; c++) { Ar[c][c] = fin[6 + c] * invN; Ai[c][c] = 0.f; }
    #pragma unroll
    for (int q = 0; q < NPAIR; q++) {
        const int c = PC[q], e = PE[q];
        const float nre = fin[12 + 4 * q + 2] * invN;
        const float nim = fin[12 + 4 * q + 3] * invN;
        Ar[c][e] = nre;  Ai[c][e] = nim;
        Ar[e][c] = nre;  Ai[e][c] = -nim;
    }
    {
        float trn = 0.f;
        #pragma unroll
        for (int c = 0; c < NC; c++) trn += Ar[c][c];
        const float eps = trn * 1e-7f + 1e-8f;
        #pragma unroll
        for (int c = 0; c < NC; c++) Ar[c][c] += eps;
    }

    // In-place unpivoted LU: L (unit diag) below, U on/above.
    #pragma unroll
    for (int k = 0; k < NC; k++) {
        const float dr = Ar[k][k], di = Ai[k][k];
        const float idn = 1.f / (dr * dr + di * di);
        const float pr = dr * idn, pi = -di * idn;
        #pragma unroll
        for (int i = k + 1; i < NC; i++) {
            const float lr = Ar[i][k] * pr - Ai[i][k] * pi;
            const float li = Ar[i][k] * pi + Ai[i][k] * pr;
            Ar[i][k] = lr; Ai[i][k] = li;
            #pragma unroll
            for (int j = k + 1; j < NC; j++) {
                Ar[i][j] -= lr * Ar[k][j] - li * Ai[k][j];
                Ai[i][j] -= lr * Ai[k][j] + li * Ar[k][j];
            }
        }
    }

    // Column-by-column solve of A x = b_j (b_j = col j of normalized psd_s).
    float trr = 1e-8f, tri = 0.f;   // TIK_EPS on real part of trace
    float w0r[NC], w0i[NC];
    #pragma unroll
    for (int j = 0; j < NC; j++) {
        float xr[NC], xi[NC];
        #pragma unroll
        for (int i = 0; i < NC; i++) {
            if (i == j)      { xr[i] = fin[j] * invS;                      xi[i] = 0.f; }
            else if (i < j)  { const int q = QIDX[i][j];
                               xr[i] = fin[12 + 4 * q] * invS;  xi[i] =  fin[13 + 4 * q] * invS; }
            else             { const int q = QIDX[j][i];
                               xr[i] = fin[12 + 4 * q] * invS;  xi[i] = -fin[13 + 4 * q] * invS; }
        }
        #pragma unroll
        for (int i = 1; i < NC; i++) {
            #pragma unroll
            for (int k = 0; k < NC - 1; k++) if (k < i) {
                xr[i] -= Ar[i][k] * xr[k] - Ai[i][k] * xi[k];
                xi[i] -= Ar[i][k] * xi[k] + Ai[i][k] * xr[k];
            }
        }
        #pragma unroll
        for (int i = NC - 1; i >= 0; i--) {
            #pragma unroll
            for (int k = 0; k < NC; k++) if (k > i) {
                xr[i] -= Ar[i][k] * xr[k] - Ai[i][k] * xi[k];
                xi[i] -= Ar[i][k] * xi[k] + Ai[i][k] * xr[k];
            }
            const float dr = Ar[i][i], di = Ai[i][i];
            const float idn = 1.f / (dr * dr + di * di);
            const float pr = dr * idn, pi = -di * idn;
            const float tr0 = xr[i] * pr - xi[i] * pi;
            xi[i] = xr[i] * pi + xi[i] * pr;
            xr[i] = tr0;
        }
        trr += xr[j]; tri += xi[j];
        if (j == 0) {
            #pragma unroll
            for (int i = 0; i < NC; i++) { w0r[i] = xr[i]; w0i[i] = xi[i]; }
        }
    }

    const float idn = 1.f / (trr * trr + tri * tri);
    #pragma unroll
    for (int c = 0; c < NC; c++) {
        const float wre = (w0r[c] * trr + w0i[c] * tri) * idn;
        const float wim = (w0i[c] * trr - w0r[c] * tri) * idn;
        wsw[gid * 12 + c]     = wre;    // conj(w): real
        wsw[gid * 12 + 6 + c] = -wim;   // conj(w): imag
    }
}

// ---------------- Kernel C: enh[t] = sum_c conj(w[c]) * spec[c,t] -----------
__global__ __launch_bounds__(BLK) void apply_kernel(
    const float* __restrict__ sr, const float* __restrict__ si,
    const float* __restrict__ wsw, float* __restrict__ out)
{
    const int bx = blockIdx.x;
    const int g  = bx >> 1;
    const int b  = g / NF;
    const int f  = g - b * NF;
    const int tb = (bx & 1) * TCH;
    const int sbase = b * NC * CS + f * NT + tb;

    const float4* s4r = (const float4*)(sr + sbase);
    const float4* s4i = (const float4*)(si + sbase);

    float wr[NC], wi[NC];
    #pragma unroll
    for (int c = 0; c < NC; c++) {
        wr[c] = wsw[g * 12 + c];
        wi[c] = wsw[g * 12 + 6 + c];
    }

    nfloat4* o4 = (nfloat4*)(out + 2 * (g * NT + tb));

    const int p = threadIdx.x;
    if (p < NP4) {
        float rr[NC][4], ii[NC][4];
        #pragma unroll
        for (int c = 0; c < NC; c++) {
            const float4 tr = s4r[c * CS4 + p];
            rr[c][0] = tr.x; rr[c][1] = tr.y; rr[c][2] = tr.z; rr[c][3] = tr.w;
            const float4 ti = s4i[c * CS4 + p];
            ii[c][0] = ti.x; ii[c][1] = ti.y; ii[c][2] = ti.z; ii[c][3] = ti.w;
        }
        float er[4], ei[4];
        #pragma unroll
        for (int k = 0; k < 4; k++) {
            float a = 0.f, bb = 0.f;
            #pragma unroll
            for (int c = 0; c < NC; c++) {
                a  += wr[c] * rr[c][k] - wi[c] * ii[c][k];
                bb += wr[c] * ii[c][k] + wi[c] * rr[c][k];
            }
            er[k] = a; ei[k] = bb;
        }
        nfloat4 o0 = {er[0], ei[0], er[1], ei[1]};
        nfloat4 o1 = {er[2], ei[2], er[3], ei[3]};
        __builtin_nontemporal_store(o0, &o4[2 * p]);
        __builtin_nontemporal_store(o1, &o4[2 * p + 1]);
    }
}

extern "C" void kernel_launch(void* const* d_in, const int* in_sizes, int n_in,
                              void* d_out, int out_size, void* d_ws, size_t ws_size,
                              hipStream_t stream) {
    const float* sr = (const float*)d_in[0];
    const float* si = (const float*)d_in[1];
    const float* ms = (const float*)d_in[2];
    const float* mn = (const float*)d_in[3];
    float* out = (float*)d_out;

    float* wsp = (float*)d_ws;                       // [NG][148] per-group even/odd partials
    float* wsw = wsp + NG * (2 * NACC);              // [NG][12] conj(w)

    psd_kernel<<<NG, 64, 0, stream>>>(sr, si, ms, mn, wsp);
    solve_kernel<<<(NG + 63) / 64, 64, 0, stream>>>(wsp, wsw);
    apply_kernel<<<NG * NCHUNK, BLK, 0, stream>>>(sr, si, wsw, out);
}

// Round 9
// 164.571 us; speedup vs baseline: 1.2227x; 1.1341x over previous
//
#include <hip/hip_runtime.h>

#define NB 4
#define NC 6
#define NF 257
#define NT 2000
#define NG (NB * NF)        // 1028 (b,f) groups
#define NPAIR 15
#define NACC 74             // [0..5] s_diag, [6..11] n_diag, [12+4q..] s_re,s_im,n_re,n_im, [72] sum_ms, [73] sum_mn
#define NCHUNK 4
#define TCH (NT / NCHUNK)   // 500 t per chunk
#define NP2 (TCH / 2)       // 250 float2 positions per chunk
#define BLK 256
#define CS  (NF * NT)       // channel stride (floats)
#define CS2 (CS / 2)        // channel stride (float2)

typedef float nfloat4 __attribute__((ext_vector_type(4)));  // native vec for nontemporal builtins

// DPP row-shift-right add: lane i += lane (i-N) within its 16-lane row
// (0 beyond row edge). VALU pipe. Data accumulates toward HIGHER lanes:
// after shr8+shr4+shr2, lane14 = row evens-sum, lane15 = row odds-sum
// (HW-verified round 7).
template<int CTRL>
__device__ __forceinline__ float dpp_add(float v) {
    int s = __builtin_amdgcn_update_dpp(0, __builtin_bit_cast(int, v), CTRL, 0xF, 0xF, true);
    return v + __builtin_bit_cast(float, s);
}

// ---------------- Kernel A: raw weighted PSD partials per (group, chunk) ----
// 4112 blocks x 256 threads (~16 waves/CU): TLP is the only lever that has
// moved this phase (r2 vs r8). One float2 per thread, one 14-load burst,
// small body (I$-friendly), no VGPR cap (two-arg launch_bounds caused the
// r4/r7 spill disasters).
__global__ __launch_bounds__(BLK) void psd_kernel(
    const float* __restrict__ sr, const float* __restrict__ si,
    const float* __restrict__ ms, const float* __restrict__ mn,
    float* __restrict__ wsp)
{
    constexpr int PC[NPAIR] = {0,0,0,0,0,1,1,1,1,2,2,2,3,3,4};
    constexpr int PE[NPAIR] = {1,2,3,4,5,2,3,4,5,3,4,5,4,5,5};

    const int bx = blockIdx.x;
    const int g  = bx >> 2;
    const int b  = g / NF;
    const int f  = g - b * NF;
    const int tb = (bx & 3) * TCH;
    const int sbase = b * NC * CS + f * NT + tb;
    const int mbase = g * NT + tb;

    const float2* s2r = (const float2*)(sr + sbase);
    const float2* s2i = (const float2*)(si + sbase);
    const float2* m2s = (const float2*)(ms + mbase);
    const float2* m2n = (const float2*)(mn + mbase);

    float acc[NACC];
    #pragma unroll
    for (int i = 0; i < NACC; i++) acc[i] = 0.f;

    // Unconditional load burst; inactive lanes load p=0 and zero their mask
    // weights (every accumulator term carries a mask factor -> contributes 0).
    const bool act = threadIdx.x < NP2;
    const int  p   = act ? threadIdx.x : 0;
    {
        float wms[2], wmn[2], rr[NC][2], ii[NC][2];
        {
            const float2 t0 = m2s[p];
            wms[0] = t0.x; wms[1] = t0.y;
            const float2 t1 = m2n[p];
            wmn[0] = t1.x; wmn[1] = t1.y;
        }
        #pragma unroll
        for (int c = 0; c < NC; c++) {
            const float2 tr = s2r[c * CS2 + p];
            rr[c][0] = tr.x; rr[c][1] = tr.y;
            const float2 ti = s2i[c * CS2 + p];
            ii[c][0] = ti.x; ii[c][1] = ti.y;
        }
        if (!act) { wms[0] = wms[1] = wmn[0] = wmn[1] = 0.f; }
        #pragma unroll
        for (int k = 0; k < 2; k++) { acc[72] += wms[k]; acc[73] += wmn[k]; }
        #pragma unroll
        for (int c = 0; c < NC; c++) {
            #pragma unroll
            for (int k = 0; k < 2; k++) {
                const float d = rr[c][k] * rr[c][k] + ii[c][k] * ii[c][k];
                acc[c]     += d * wms[k];
                acc[6 + c] += d * wmn[k];
            }
        }
        #pragma unroll
        for (int q = 0; q < NPAIR; q++) {
            const int c = PC[q], e = PE[q];
            #pragma unroll
            for (int k = 0; k < 2; k++) {
                const float cr = rr[c][k] * rr[e][k] + ii[c][k] * ii[e][k];
                const float ci = ii[c][k] * rr[e][k] - rr[c][k] * ii[e][k];
                acc[12 + 4 * q + 0] += cr * wms[k];
                acc[12 + 4 * q + 1] += ci * wms[k];
                acc[12 + 4 * q + 2] += cr * wmn[k];
                acc[12 + 4 * q + 3] += ci * wmn[k];
            }
        }
    }

    // In-row DPP reduction (VALU pipe): lane14 = row evens-sum, lane15 = odds.
    #pragma unroll
    for (int i = 0; i < NACC; i++) {
        float v = acc[i];
        v = dpp_add<0x118>(v);   // row_shr:8
        v = dpp_add<0x114>(v);   // row_shr:4
        v = dpp_add<0x112>(v);   // row_shr:2
        acc[i] = v;
    }

    __shared__ float red[32][NACC];
    const int lane16 = threadIdx.x & 15;
    const int ridx   = ((threadIdx.x >> 4) << 1) | (lane16 & 1);  // 0..31
    if (lane16 >= 14) {
        #pragma unroll
        for (int i = 0; i < NACC; i++) red[ridx][i] = acc[i];
    }
    __syncthreads();

    if (threadIdx.x < NACC) {
        float s = 0.f;
        #pragma unroll
        for (int r = 0; r < 32; r++) s += red[r][threadIdx.x];
        wsp[bx * NACC + threadIdx.x] = s;
    }
}

// ---------------- Kernel B: one thread per (b,f) — LU + column solves -------
// launch_bounds(64,1): high VGPR allowed so nothing spills (round-4 lesson).
__global__ __launch_bounds__(64, 1) void solve_kernel(
    const float* __restrict__ wsp, float* __restrict__ wsw)
{
    const int gid = blockIdx.x * 64 + threadIdx.x;
    if (gid >= NG) return;

    constexpr int PC[NPAIR] = {0,0,0,0,0,1,1,1,1,2,2,2,3,3,4};
    constexpr int PE[NPAIR] = {1,2,3,4,5,2,3,4,5,3,4,5,4,5,5};
    constexpr int QIDX[NC][NC] = {
        {-1, 0, 1, 2, 3, 4},
        {-1,-1, 5, 6, 7, 8},
        {-1,-1,-1, 9,10,11},
        {-1,-1,-1,-1,12,13},
        {-1,-1,-1,-1,-1,14},
        {-1,-1,-1,-1,-1,-1}};

    const float* p0 = wsp + (NCHUNK * gid) * NACC;
    float fin[NACC];
    #pragma unroll
    for (int i = 0; i < NACC; i++)
        fin[i] = (p0[i] + p0[NACC + i]) + (p0[2 * NACC + i] + p0[3 * NACC + i]);

    const float invS = 1.f / (fin[72] + 1e-15f);
    const float invN = 1.f / (fin[73] + 1e-15f);

    // A = normalized psd_n + eps*I
    float Ar[NC][NC], Ai[NC][NC];
    #pragma unroll
    for (int c = 0; c < NC; c++) { Ar[c][c] = fin[6 + c] * invN; Ai[c][c] = 0.f; }
    #pragma unroll
    for (int q = 0; q < NPAIR; q++) {
        const int c = PC[q], e = PE[q];
        const float nre = fin[12 + 4 * q + 2] * invN;
        const float nim = fin[12 + 4 * q + 3] * invN;
        Ar[c][e] = nre;  Ai[c][e] = nim;
        Ar[e][c] = nre;  Ai[e][c] = -nim;
    }
    {
        float trn = 0.f;
        #pragma unroll
        for (int c = 0; c < NC; c++) trn += Ar[c][c];
        const float eps = trn * 1e-7f + 1e-8f;
        #pragma unroll
        for (int c = 0; c < NC; c++) Ar[c][c] += eps;
    }

    // In-place unpivoted LU: L (unit diag) below, U on/above.
    #pragma unroll
    for (int k = 0; k < NC; k++) {
        const float dr = Ar[k][k], di = Ai[k][k];
        const float idn = 1.f / (dr * dr + di * di);
        const float pr = dr * idn, pi = -di * idn;
        #pragma unroll
        for (int i = k + 1; i < NC; i++) {
            const float lr = Ar[i][k] * pr - Ai[i][k] * pi;
            const float li = Ar[i][k] * pi + Ai[i][k] * pr;
            Ar[i][k] = lr; Ai[i][k] = li;
            #pragma unroll
            for (int j = k + 1; j < NC; j++) {
                Ar[i][j] -= lr * Ar[k][j] - li * Ai[k][j];
                Ai[i][j] -= lr * Ai[k][j] + li * Ar[k][j];
            }
        }
    }

    // Column-by-column solve of A x = b_j (b_j = col j of normalized psd_s).
    float trr = 1e-8f, tri = 0.f;   // TIK_EPS on real part of trace
    float w0r[NC], w0i[NC];
    #pragma unroll
    for (int j = 0; j < NC; j++) {
        float xr[NC], xi[NC];
        #pragma unroll
        for (int i = 0; i < NC; i++) {
            if (i == j)      { xr[i] = fin[j] * invS;                      xi[i] = 0.f; }
            else if (i < j)  { const int q = QIDX[i][j];
                               xr[i] = fin[12 + 4 * q] * invS;  xi[i] =  fin[13 + 4 * q] * invS; }
            else             { const int q = QIDX[j][i];
                               xr[i] = fin[12 + 4 * q] * invS;  xi[i] = -fin[13 + 4 * q] * invS; }
        }
        #pragma unroll
        for (int i = 1; i < NC; i++) {
            #pragma unroll
            for (int k = 0; k < NC - 1; k++) if (k < i) {
                xr[i] -= Ar[i][k] * xr[k] - Ai[i][k] * xi[k];
                xi[i] -= Ar[i][k] * xi[k] + Ai[i][k] * xr[k];
            }
        }
        #pragma unroll
        for (int i = NC - 1; i >= 0; i--) {
            #pragma unroll
            for (int k = 0; k < NC; k++) if (k > i) {
                xr[i] -= Ar[i][k] * xr[k] - Ai[i][k] * xi[k];
                xi[i] -= Ar[i][k] * xi[k] + Ai[i][k] * xr[k];
            }
            const float dr = Ar[i][i], di = Ai[i][i];
            const float idn = 1.f / (dr * dr + di * di);
            const float pr = dr * idn, pi = -di * idn;
            const float tr0 = xr[i] * pr - xi[i] * pi;
            xi[i] = xr[i] * pi + xi[i] * pr;
            xr[i] = tr0;
        }
        trr += xr[j]; tri += xi[j];
        if (j == 0) {
            #pragma unroll
            for (int i = 0; i < NC; i++) { w0r[i] = xr[i]; w0i[i] = xi[i]; }
        }
    }

    const float idn = 1.f / (trr * trr + tri * tri);
    #pragma unroll
    for (int c = 0; c < NC; c++) {
        const float wre = (w0r[c] * trr + w0i[c] * tri) * idn;
        const float wim = (w0i[c] * trr - w0r[c] * tri) * idn;
        wsw[gid * 12 + c]     = wre;    // conj(w): real
        wsw[gid * 12 + 6 + c] = -wim;   // conj(w): imag
    }
}

// ---------------- Kernel C: enh[t] = sum_c conj(w[c]) * spec[c,t] -----------
__global__ __launch_bounds__(BLK) void apply_kernel(
    const float* __restrict__ sr, const float* __restrict__ si,
    const float* __restrict__ wsw, float* __restrict__ out)
{
    const int bx = blockIdx.x;
    const int g  = bx >> 2;
    const int b  = g / NF;
    const int f  = g - b * NF;
    const int tb = (bx & 3) * TCH;
    const int sbase = b * NC * CS + f * NT + tb;

    const float2* s2r = (const float2*)(sr + sbase);
    const float2* s2i = (const float2*)(si + sbase);

    float wr[NC], wi[NC];
    #pragma unroll
    for (int c = 0; c < NC; c++) {
        wr[c] = wsw[g * 12 + c];
        wi[c] = wsw[g * 12 + 6 + c];
    }

    nfloat4* o4 = (nfloat4*)(out + 2 * (g * NT + tb));

    const int p = threadIdx.x;
    if (p < NP2) {
        float rr[NC][2], ii[NC][2];
        #pragma unroll
        for (int c = 0; c < NC; c++) {
            const float2 tr = s2r[c * CS2 + p];
            rr[c][0] = tr.x; rr[c][1] = tr.y;
            const float2 ti = s2i[c * CS2 + p];
            ii[c][0] = ti.x; ii[c][1] = ti.y;
        }
        float er[2], ei[2];
        #pragma unroll
        for (int k = 0; k < 2; k++) {
            float a = 0.f, bb = 0.f;
            #pragma unroll
            for (int c = 0; c < NC; c++) {
                a  += wr[c] * rr[c][k] - wi[c] * ii[c][k];
                bb += wr[c] * ii[c][k] + wi[c] * rr[c][k];
            }
            er[k] = a; ei[k] = bb;
        }
        nfloat4 o0 = {er[0], ei[0], er[1], ei[1]};
        __builtin_nontemporal_store(o0, &o4[p]);
    }
}

extern "C" void kernel_launch(void* const* d_in, const int* in_sizes, int n_in,
                              void* d_out, int out_size, void* d_ws, size_t ws_size,
                              hipStream_t stream) {
    const float* sr = (const float*)d_in[0];
    const float* si = (const float*)d_in[1];
    const float* ms = (const float*)d_in[2];
    const float* mn = (const float*)d_in[3];
    float* out = (float*)d_out;

    float* wsp = (float*)d_ws;                       // [NG*NCHUNK][NACC] partials
    float* wsw = wsp + NG * NCHUNK * NACC;           // [NG][12] conj(w)

    psd_kernel<<<NG * NCHUNK, BLK, 0, stream>>>(sr, si, ms, mn, wsp);
    solve_kernel<<<(NG + 63) / 64, 64, 0, stream>>>(wsp, wsw);
    apply_kernel<<<NG * NCHUNK, BLK, 0, stream>>>(sr, si, wsw, out);
}